// Round 5
// baseline (189.876 us; speedup 1.0000x reference)
//
#include <hip/hip_runtime.h>

#define W 1024
#define H 1024
#define NB 16
#define TX 32           // tile width
#define STEP 32         // output rows per step
#define HRING 38        // ring rows = STEP + 6 halo
#define YSEG 256        // output rows per block
#define NSTEP (YSEG / STEP)
#define CH_STRIDE (HRING * TX)  // floats per channel plane in hbuf

// Horizontal 7-tap conv of the 8 SSIM product channels for one image row,
// 4 output columns, writing float4 per channel into the LDS ring buffer.
__device__ __forceinline__ void hconv_row(
    const float* __restrict__ p1, const float* __restrict__ p2,
    const float* __restrict__ p3, int gy, int gx0, bool xfast,
    const float* __restrict__ g, float* __restrict__ dst /* &hbuf[0][rr][c0] */)
{
    float acc[8][4];
    #pragma unroll
    for (int ch = 0; ch < 8; ++ch)
        #pragma unroll
        for (int j = 0; j < 4; ++j) acc[ch][j] = 0.0f;

    if ((gy >= 0) & (gy < H)) {
        const size_t rowoff = (size_t)gy * W;
        float V1[12], V2[12], V3[12];
        if (xfast) {
            const float* q1 = p1 + rowoff + gx0;
            const float* q2 = p2 + rowoff + gx0;
            const float* q3 = p3 + rowoff + gx0;
            *(float4*)&V1[0] = *(const float4*)(q1);
            *(float4*)&V1[4] = *(const float4*)(q1 + 4);
            *(float4*)&V1[8] = *(const float4*)(q1 + 8);
            *(float4*)&V2[0] = *(const float4*)(q2);
            *(float4*)&V2[4] = *(const float4*)(q2 + 4);
            *(float4*)&V2[8] = *(const float4*)(q2 + 8);
            *(float4*)&V3[0] = *(const float4*)(q3);
            *(float4*)&V3[4] = *(const float4*)(q3 + 4);
            *(float4*)&V3[8] = *(const float4*)(q3 + 8);
        } else {
            #pragma unroll
            for (int c = 0; c < 12; ++c) {
                const int x = gx0 + c;
                const bool ok = (x >= 0) & (x < W);
                const size_t off = rowoff + x;
                V1[c] = ok ? p1[off] : 0.0f;
                V2[c] = ok ? p2[off] : 0.0f;
                V3[c] = ok ? p3[off] : 0.0f;
            }
        }
        #pragma unroll
        for (int j = 0; j < 4; ++j) {
            #pragma unroll
            for (int dx = 0; dx < 7; ++dx) {
                const float wg = g[dx];
                const float v1 = V1[1 + j + dx];
                const float v2 = V2[1 + j + dx];
                const float v3 = V3[1 + j + dx];
                const float t1 = wg * v1;
                const float t2 = wg * v2;
                const float t3 = wg * v3;
                acc[0][j] += t1;
                acc[1][j] += t2;
                acc[2][j] += t3;
                acc[3][j] += t1 * v1;
                acc[4][j] += t2 * v2;
                acc[5][j] += t3 * v3;
                acc[6][j] += t1 * v2;
                acc[7][j] += t1 * v3;
            }
        }
    }
    #pragma unroll
    for (int ch = 0; ch < 8; ++ch)
        *(float4*)(dst + ch * CH_STRIDE) =
            make_float4(acc[ch][0], acc[ch][1], acc[ch][2], acc[ch][3]);
}

// Fused SSIM: each block walks a 32-col x 256-row segment in 8 steps of 32
// rows, keeping a 38-row ring of h-conv results in LDS. Stage B per step is
// exactly 256 balanced tasks; Stage C is 4-tall vertical conv + SSIM map.
__global__ __launch_bounds__(256, 4) void ssim_main(
    const float* __restrict__ img1, const float* __restrict__ img2,
    const float* __restrict__ img3, const float* __restrict__ win,
    float* __restrict__ partial)
{
    __shared__ __align__(16) float hbuf[8][HRING][TX];  // 38912 B
    __shared__ float wavesum[4];

    const int tid = threadIdx.x;
    const int x0  = blockIdx.x * TX;
    const int ys0 = blockIdx.y * YSEG;
    const size_t imoff = (size_t)blockIdx.z * (size_t)(W * H);
    const float* p1 = img1 + imoff;
    const float* p2 = img2 + imoff;
    const float* p3 = img3 + imoff;

    // Separable 1-D gaussian from the 2-D window: g[j] = win[3][j]/sqrt(win[3][3])
    float g[7];
    {
        const float g3 = sqrtf(win[24]);
        #pragma unroll
        for (int j = 0; j < 7; ++j) g[j] = win[21 + j] / g3;
    }

    // ---- Stage-B fixed per-thread geometry ----
    const int br   = tid >> 3;            // 0..31 row-within-step
    const int bc0  = (tid & 7) << 2;      // 0,4,...,28
    const int bgx0 = x0 + bc0 - 4;
    const bool xfast = (bgx0 >= 0) & (bgx0 + 12 <= W);

    // ---- prime ring rows 0..5 (h-rows ys0-3 .. ys0+2); disjoint from B(0) ----
    if (tid < 48) {
        const int pr  = tid >> 3;         // 0..5
        const int pc0 = (tid & 7) << 2;
        const int pgx0 = x0 + pc0 - 4;
        const bool pxf = (pgx0 >= 0) & (pgx0 + 12 <= W);
        hconv_row(p1, p2, p3, ys0 - 3 + pr, pgx0, pxf, g, &hbuf[0][pr][pc0]);
    }

    // ---- Stage-C fixed per-thread geometry ----
    const int tx  = tid & 31;
    const int cr0 = (tid >> 5) << 2;      // 0,4,...,28

    int rrB = 6 + br;                     // ring row of this thread's B task
    int gyB = ys0 + 3 + br;               // image row of this thread's B task
    int arC = cr0;                        // ring row of first needed C h-row

    float lsum = 0.0f;
    float* const hb = &hbuf[0][0][0];

    for (int s = 0; s < NSTEP; ++s) {
        // ---- Stage B: h-conv 32 new rows into the ring ----
        hconv_row(p1, p2, p3, gyB, bgx0, xfast, g, &hbuf[0][rrB][bc0]);
        __syncthreads();

        // ---- Stage C: vertical conv (4-tall) + SSIM ----
        int offs[10];
        #pragma unroll
        for (int dy = 0; dy < 10; ++dy) {
            int r = arC + dy;
            if (r >= HRING) r -= HRING;
            offs[dy] = r * TX + tx;
        }
        float sacc[8][4];
        #pragma unroll
        for (int ch = 0; ch < 8; ++ch) {
            float v[10];
            #pragma unroll
            for (int dy = 0; dy < 10; ++dy) v[dy] = hb[ch * CH_STRIDE + offs[dy]];
            #pragma unroll
            for (int j = 0; j < 4; ++j) {
                float t = 0.0f;
                #pragma unroll
                for (int dy = 0; dy < 7; ++dy) t += g[dy] * v[j + dy];
                sacc[ch][j] = t;
            }
        }
        #pragma unroll
        for (int j = 0; j < 4; ++j) {
            const float mu1 = sacc[0][j], mu2 = sacc[1][j], mu3 = sacc[2][j];
            const float sig1  = sacc[3][j] - mu1 * mu1;
            const float sig2  = sacc[4][j] - mu2 * mu2;
            const float sig3  = sacc[5][j] - mu3 * mu3;
            const float sig12 = sacc[6][j] - mu1 * mu2;
            const float sig13 = sacc[7][j] - mu1 * mu3;
            const float C2 = 9.0e-4f;  // 0.03^2
            const float m12 = (2.0f * sig12 + C2) / (sig1 + sig2 + C2);
            const float m13 = (2.0f * sig13 + C2) / (sig1 + sig3 + C2);
            lsum += (mu2 > mu3) ? m12 : m13;
        }
        __syncthreads();  // protect ring rows read by C from next-step B writes

        rrB += STEP; if (rrB >= HRING) rrB -= HRING;
        gyB += STEP;
        arC += STEP; if (arC >= HRING) arC -= HRING;
    }

    // ---- Block reduction (deterministic) ----
    #pragma unroll
    for (int o = 32; o > 0; o >>= 1) lsum += __shfl_down(lsum, o, 64);
    if ((tid & 63) == 0) wavesum[tid >> 6] = lsum;
    __syncthreads();
    if (tid == 0) {
        const float t = (wavesum[0] + wavesum[1]) + (wavesum[2] + wavesum[3]);
        partial[((size_t)blockIdx.z * gridDim.y + blockIdx.y) * gridDim.x + blockIdx.x] = t;
    }
}

// Deterministic final reduction: one block, fixed summation order, f64 accum.
__global__ __launch_bounds__(256) void ssim_reduce(
    const float* __restrict__ partial, float* __restrict__ out, int n)
{
    __shared__ double sh[256];
    const int tid = threadIdx.x;
    double s = 0.0;
    for (int i = tid; i < n; i += 256) s += (double)partial[i];
    sh[tid] = s;
    __syncthreads();
    for (int o = 128; o > 0; o >>= 1) {
        if (tid < o) sh[tid] += sh[tid + o];
        __syncthreads();
    }
    if (tid == 0) out[0] = (float)(sh[0] / (double)((size_t)NB * W * H));
}

extern "C" void kernel_launch(void* const* d_in, const int* in_sizes, int n_in,
                              void* d_out, int out_size, void* d_ws, size_t ws_size,
                              hipStream_t stream) {
    const float* img1 = (const float*)d_in[0];
    const float* img2 = (const float*)d_in[1];
    const float* img3 = (const float*)d_in[2];
    const float* win  = (const float*)d_in[3];
    float* out = (float*)d_out;
    float* partial = (float*)d_ws;

    dim3 grid(W / TX, H / YSEG, NB);  // 32 x 4 x 16 = 2048 blocks
    ssim_main<<<grid, 256, 0, stream>>>(img1, img2, img3, win, partial);

    const int nblk = (W / TX) * (H / YSEG) * NB;
    ssim_reduce<<<1, 256, 0, stream>>>(partial, out, nblk);
}

// Round 6
// 128.445 us; speedup vs baseline: 1.4783x; 1.4783x over previous
//
#include <hip/hip_runtime.h>

typedef float v2f __attribute__((ext_vector_type(2)));

#define W 1024
#define H 1024
#define NB 16
#define TX 32
#define TY 18
#define HR 24               // TY + 6 h-conv rows per block
#define NTH 192             // 3 waves
#define YBLK ((H + TY - 1) / TY)   // 57 (last block 2 rows OOB, guarded)
#define RSTRIDE (8 * TX)    // dwords per h-row: 8 channels x 32 cols

// Fused SSIM, packed-FP32 version.
//   hbuf layout: [HR][8 channels][TX] floats -> channel pairs 32 dwords apart
//   (ds_read2_b32-mergeable), rows 256 dwords apart.
//   Stage B: 192 tasks = 24 rows x 8 col-groups, one per thread. Horizontal
//            7-tap conv of 8 product channels for 4 output cols, computed as
//            2x v2f (j01, j23) with a weight-pair table gp[m]={g[m-1],g[m-2]}
//            so V[m] broadcasts (op_sel) -- no pair-building movs.
//   Stage C: 32 cols x 6 rowgroups x 3-tall. Vertical conv packed across
//            channel pairs; SSIM map; deterministic reduction.
__global__ __launch_bounds__(NTH, 4) void ssim_main(
    const float* __restrict__ img1, const float* __restrict__ img2,
    const float* __restrict__ img3, const float* __restrict__ win,
    float* __restrict__ partial)
{
    __shared__ __align__(16) float hbuf[HR * RSTRIDE];  // 24576 B
    __shared__ float wavesum[3];

    const int tid = threadIdx.x;
    const int x0  = blockIdx.x * TX;
    const int ys0 = blockIdx.y * TY;
    const size_t imoff = (size_t)blockIdx.z * (size_t)(W * H);
    const float* p1 = img1 + imoff;
    const float* p2 = img2 + imoff;
    const float* p3 = img3 + imoff;

    // Separable 1-D gaussian: g[j] = win[3][j] / sqrt(win[3][3])
    float g[7];
    {
        const float inv = 1.0f / sqrtf(win[24]);
        #pragma unroll
        for (int j = 0; j < 7; ++j) g[j] = win[21 + j] * inv;
    }

    // ---- Stage B: horizontal conv, global -> LDS (1 task per thread) ----
    {
        const int br  = tid >> 3;            // 0..23  h-row within block
        const int bc0 = (tid & 7) << 2;      // 0,4,...,28
        const int gy  = ys0 + br - 3;
        const int gx0 = x0 + bc0 - 4;
        const bool xfast = (gx0 >= 0) & (gx0 + 12 <= W);

        v2f accA[8], accB[8];                // j=(0,1) and j=(2,3)
        #pragma unroll
        for (int ch = 0; ch < 8; ++ch) { accA[ch] = (v2f)0.0f; accB[ch] = (v2f)0.0f; }

        if ((gy >= 0) & (gy < H)) {
            const size_t rowoff = (size_t)gy * W;
            float V1[12], V2[12], V3[12];
            if (xfast) {
                const float* q1 = p1 + rowoff + gx0;
                const float* q2 = p2 + rowoff + gx0;
                const float* q3 = p3 + rowoff + gx0;
                *(float4*)&V1[0] = *(const float4*)(q1);
                *(float4*)&V1[4] = *(const float4*)(q1 + 4);
                *(float4*)&V1[8] = *(const float4*)(q1 + 8);
                *(float4*)&V2[0] = *(const float4*)(q2);
                *(float4*)&V2[4] = *(const float4*)(q2 + 4);
                *(float4*)&V2[8] = *(const float4*)(q2 + 8);
                *(float4*)&V3[0] = *(const float4*)(q3);
                *(float4*)&V3[4] = *(const float4*)(q3 + 4);
                *(float4*)&V3[8] = *(const float4*)(q3 + 8);
            } else {
                #pragma unroll
                for (int c = 0; c < 12; ++c) {
                    const int x = gx0 + c;
                    const bool ok = (x >= 0) & (x < W);
                    const size_t off = rowoff + x;
                    V1[c] = ok ? p1[off] : 0.0f;
                    V2[c] = ok ? p2[off] : 0.0f;
                    V3[c] = ok ? p3[off] : 0.0f;
                }
            }

            // weight-pair table: out[j] = sum_k g[k-1-j]*V[k]
            v2f gp[8];
            gp[0] = (v2f){g[0], 0.0f};
            #pragma unroll
            for (int m = 2; m <= 7; ++m) gp[m - 1] = (v2f){g[m - 1], g[m - 2]};
            gp[7] = (v2f){0.0f, g[6]};

            #pragma unroll
            for (int m = 1; m <= 8; ++m) {
                const v2f w = gp[m - 1];
                const float vA1 = V1[m], vA2 = V2[m], vA3 = V3[m];
                const float vB1 = V1[m + 2], vB2 = V2[m + 2], vB3 = V3[m + 2];
                v2f t;
                t = w * vA1; accA[0] += t; accA[3] += t * vA1; accA[6] += t * vA2; accA[7] += t * vA3;
                t = w * vA2; accA[1] += t; accA[4] += t * vA2;
                t = w * vA3; accA[2] += t; accA[5] += t * vA3;
                t = w * vB1; accB[0] += t; accB[3] += t * vB1; accB[6] += t * vB2; accB[7] += t * vB3;
                t = w * vB2; accB[1] += t; accB[4] += t * vB2;
                t = w * vB3; accB[2] += t; accB[5] += t * vB3;
            }
        }
        // write: row br, channel ch, cols bc0..bc0+3 (2x b64 per channel)
        const int wbase = br * RSTRIDE + bc0;
        #pragma unroll
        for (int ch = 0; ch < 8; ++ch) {
            *(v2f*)&hbuf[wbase + ch * TX]     = accA[ch];
            *(v2f*)&hbuf[wbase + ch * TX + 2] = accB[ch];
        }
    }
    __syncthreads();

    // ---- Stage C: vertical conv (3-tall), packed across channel pairs ----
    const int tx = tid & 31;
    const int rg = tid >> 5;        // 0..5
    const int r0 = rg * 3;

    v2f s[4][3];
    #pragma unroll
    for (int cp = 0; cp < 4; ++cp)
        #pragma unroll
        for (int j = 0; j < 3; ++j) s[cp][j] = (v2f)0.0f;

    int base = r0 * RSTRIDE + tx;
    #pragma unroll
    for (int dy = 0; dy < 9; ++dy) {
        v2f p[4];
        #pragma unroll
        for (int cp = 0; cp < 4; ++cp) {
            p[cp].x = hbuf[base + cp * 64];        // channel 2cp
            p[cp].y = hbuf[base + cp * 64 + 32];   // channel 2cp+1
        }
        #pragma unroll
        for (int j = 0; j < 3; ++j) {
            const int dd = dy - j;
            if (dd >= 0 && dd < 7) {
                const float wg = g[dd];
                #pragma unroll
                for (int cp = 0; cp < 4; ++cp) s[cp][j] += wg * p[cp];
            }
        }
        base += RSTRIDE;
    }

    float lsum = 0.0f;
    #pragma unroll
    for (int j = 0; j < 3; ++j) {
        if (ys0 + r0 + j < H) {
            const float mu1 = s[0][j].x, mu2 = s[0][j].y;
            const float mu3 = s[1][j].x, E11 = s[1][j].y;
            const float E22 = s[2][j].x, E33 = s[2][j].y;
            const float E12 = s[3][j].x, E13 = s[3][j].y;
            const float sig1  = E11 - mu1 * mu1;
            const float sig2  = E22 - mu2 * mu2;
            const float sig3  = E33 - mu3 * mu3;
            const float sig12 = E12 - mu1 * mu2;
            const float sig13 = E13 - mu1 * mu3;
            const float C2 = 9.0e-4f;  // 0.03^2
            const float m12 = (2.0f * sig12 + C2) * __builtin_amdgcn_rcpf(sig1 + sig2 + C2);
            const float m13 = (2.0f * sig13 + C2) * __builtin_amdgcn_rcpf(sig1 + sig3 + C2);
            lsum += (mu2 > mu3) ? m12 : m13;
        }
    }

    // ---- Block reduction (deterministic) ----
    #pragma unroll
    for (int o = 32; o > 0; o >>= 1) lsum += __shfl_down(lsum, o, 64);
    if ((tid & 63) == 0) wavesum[tid >> 6] = lsum;
    __syncthreads();
    if (tid == 0) {
        partial[((size_t)blockIdx.z * gridDim.y + blockIdx.y) * gridDim.x + blockIdx.x] =
            wavesum[0] + wavesum[1] + wavesum[2];
    }
}

// Deterministic final reduction: one block, fixed summation order, f64 accum.
__global__ __launch_bounds__(256) void ssim_reduce(
    const float* __restrict__ partial, float* __restrict__ out, int n)
{
    __shared__ double sh[256];
    const int tid = threadIdx.x;
    double s = 0.0;
    for (int i = tid; i < n; i += 256) s += (double)partial[i];
    sh[tid] = s;
    __syncthreads();
    for (int o = 128; o > 0; o >>= 1) {
        if (tid < o) sh[tid] += sh[tid + o];
        __syncthreads();
    }
    if (tid == 0) out[0] = (float)(sh[0] / (double)((size_t)NB * W * H));
}

extern "C" void kernel_launch(void* const* d_in, const int* in_sizes, int n_in,
                              void* d_out, int out_size, void* d_ws, size_t ws_size,
                              hipStream_t stream) {
    const float* img1 = (const float*)d_in[0];
    const float* img2 = (const float*)d_in[1];
    const float* img3 = (const float*)d_in[2];
    const float* win  = (const float*)d_in[3];
    float* out = (float*)d_out;
    float* partial = (float*)d_ws;

    dim3 grid(W / TX, YBLK, NB);  // 32 x 57 x 16 = 29184 blocks
    ssim_main<<<grid, NTH, 0, stream>>>(img1, img2, img3, win, partial);

    const int nblk = (W / TX) * YBLK * NB;
    ssim_reduce<<<1, 256, 0, stream>>>(partial, out, nblk);
}